// Round 6
// baseline (939.387 us; speedup 1.0000x reference)
//
#include <hip/hip_runtime.h>
#include <cstdint>
#include <cstddef>

// ---------------------------------------------------------------------------
// Mamba BC network forward.
//  - Split-precision bf16 MFMA GEMMs (hi/lo 3-pass) with 2-phase reg prefetch
//  - dt computed once in scan_p1 (fused dt_proj+softplus), stored, reused in p3
//  - chunked selective scan LC=32/NC=32, PF=8 double-buffered load prefetch
// B=8, L=1024, D_MODEL=512, D_INNER=1024, D_STATE=16, D_CONV=4, DT_RANK=32, 3 layers.
// ---------------------------------------------------------------------------

#define DEVI static __device__ __forceinline__

using short8 = __attribute__((ext_vector_type(8))) short;
using f32x4  = __attribute__((ext_vector_type(4))) float;
typedef unsigned short ushort;
typedef unsigned int uint;

DEVI float sigmoidf_(float x) { return 1.f / (1.f + __expf(-x)); }
DEVI float siluf_(float x)    { return x * sigmoidf_(x); }
DEVI float softplusf_(float x){ return fmaxf(x, 0.f) + log1pf(expf(-fabsf(x))); }

DEVI ushort rne_bf16(float f) {
    uint u = __float_as_uint(f);
    return (ushort)((u + 0x7fffu + ((u >> 16) & 1u)) >> 16);
}
DEVI float bf16_to_f(ushort h) { return __uint_as_float(((uint)h) << 16); }

constexpr int LC = 32;   // scan chunk length
constexpr int NC = 32;   // number of chunks (1024 / 32)
constexpr int PF = 8;    // prefetch batch

// ---------------------------------------------------------------------------
// Weight conversion: fp32 -> bf16 hi plane + bf16 lo plane (lo = x - hi).
// ---------------------------------------------------------------------------
DEVI void cvt4(const float4 v, ushort* h, ushort* l) {
    const float vv[4] = {v.x, v.y, v.z, v.w};
    #pragma unroll
    for (int e = 0; e < 4; e++) {
        const ushort hh = rne_bf16(vv[e]);
        h[e] = hh;
        l[e] = rne_bf16(vv[e] - bf16_to_f(hh));
    }
}

__global__ __launch_bounds__(256)
void wcvt_kernel(const float* __restrict__ src, ushort* __restrict__ hi,
                 ushort* __restrict__ lo, int n4)
{
    const int idx = blockIdx.x * 256 + threadIdx.x;
    if (idx >= n4) return;
    const float4 v = reinterpret_cast<const float4*>(src)[idx];
    ushort h[4], l[4];
    cvt4(v, h, l);
    *reinterpret_cast<ushort4*>(&hi[idx * 4]) = make_ushort4(h[0], h[1], h[2], h[3]);
    *reinterpret_cast<ushort4*>(&lo[idx * 4]) = make_ushort4(l[0], l[1], l[2], l[3]);
}

// Converts one layer's in_proj (1048576), out_proj (524288), x_proj (65536)
// weights into packed hi/lo planes inside dst (ushort offsets):
// in_hi 0 | in_lo 1048576 | out_hi 2097152 | out_lo 2621440 |
// xp_hi 3145728 | xp_lo 3211264   (total 3276800 ushorts)
__global__ __launch_bounds__(256)
void wcvt3_kernel(const float* __restrict__ s_in, const float* __restrict__ s_out,
                  const float* __restrict__ s_xp, ushort* __restrict__ dst)
{
    const int idx = blockIdx.x * 256 + threadIdx.x;   // 409600 float4 units
    if (idx >= 409600) return;
    const int e0 = idx * 4;
    const float* src; ushort* hb; ushort* lb; int loc;
    if (e0 < 1048576)      { src = s_in;  hb = dst;           lb = dst + 1048576; loc = e0; }
    else if (e0 < 1572864) { src = s_out; hb = dst + 2097152; lb = dst + 2621440; loc = e0 - 1048576; }
    else                   { src = s_xp;  hb = dst + 3145728; lb = dst + 3211264; loc = e0 - 1572864; }
    const float4 v = *reinterpret_cast<const float4*>(&src[loc]);
    ushort h[4], l[4];
    cvt4(v, h, l);
    *reinterpret_cast<ushort4*>(&hb[loc]) = make_ushort4(h[0], h[1], h[2], h[3]);
    *reinterpret_cast<ushort4*>(&lb[loc]) = make_ushort4(l[0], l[1], l[2], l[3]);
}

// ---------------------------------------------------------------------------
// Split-precision bf16 MFMA GEMM with 2-phase register prefetch:
// C[m,n] = sum_k A[m,k]*W[n,k] (+bias). 128x128 tile, BK=32, 4 waves (2x2).
// ACT: 0 none, 1 +bias.
// ---------------------------------------------------------------------------
template<int ACT>
__global__ __launch_bounds__(256)
void gemm_mfma(const float* __restrict__ A, int lda,
               const ushort* __restrict__ Whi, const ushort* __restrict__ Wlo,
               int ldw, const float* __restrict__ bias,
               float* __restrict__ C, int ldc, int K)
{
    __shared__ short As_hi[4096], As_lo[4096], Ws_hi[4096], Ws_lo[4096]; // 32 KB

    const int tid  = threadIdx.x;
    const int lane = tid & 63;
    const int wave = tid >> 6;
    const int wr   = wave >> 1;
    const int wc   = wave & 1;
    const int row0 = blockIdx.y * 128;
    const int col0 = blockIdx.x * 128;

    const int g  = tid & 3;
    const int r0 = tid >> 2;

    const int lg = lane >> 4;
    const int lm = lane & 15;
    const int chA = lg * 128 + ((wr * 64 + lm) ^ lg);
    const int chB = lg * 128 + ((wc * 64 + lm) ^ lg);

    f32x4 acc[4][4];
    #pragma unroll
    for (int i = 0; i < 4; i++)
        #pragma unroll
        for (int j = 0; j < 4; j++) acc[i][j] = (f32x4){0.f, 0.f, 0.f, 0.f};

    float4 av0[2], av1[2];
    short8 wh[2], wl8[2];

    auto gload = [&](int k0) {
        #pragma unroll
        for (int p = 0; p < 2; p++) {
            const int rr = r0 + p * 64;
            const float* ap = A + (size_t)(row0 + rr) * lda + k0 + g * 8;
            av0[p] = *reinterpret_cast<const float4*>(ap);
            av1[p] = *reinterpret_cast<const float4*>(ap + 4);
            const size_t wo = (size_t)(col0 + rr) * ldw + k0 + g * 8;
            wh[p]  = *reinterpret_cast<const short8*>(&Whi[wo]);
            wl8[p] = *reinterpret_cast<const short8*>(&Wlo[wo]);
        }
    };

    gload(0);

    for (int k0 = 0; k0 < K; k0 += 32) {
        #pragma unroll
        for (int p = 0; p < 2; p++) {
            const int ch = g * 128 + ((r0 + p * 64) ^ g);
            ushort h[8], l[8];
            cvt4(av0[p], h, l);
            cvt4(av1[p], h + 4, l + 4);
            short8 h8, l8;
            #pragma unroll
            for (int e = 0; e < 8; e++) { h8[e] = (short)h[e]; l8[e] = (short)l[e]; }
            *reinterpret_cast<short8*>(&As_hi[ch * 8]) = h8;
            *reinterpret_cast<short8*>(&As_lo[ch * 8]) = l8;
            *reinterpret_cast<short8*>(&Ws_hi[ch * 8]) = wh[p];
            *reinterpret_cast<short8*>(&Ws_lo[ch * 8]) = wl8[p];
        }
        if (k0 + 32 < K) gload(k0 + 32);   // in flight during barrier+MFMA
        __syncthreads();

        short8 a_hi[4], a_lo[4], b_hi[4], b_lo[4];
        #pragma unroll
        for (int i = 0; i < 4; i++) {
            a_hi[i] = *reinterpret_cast<const short8*>(&As_hi[(chA + i * 16) * 8]);
            a_lo[i] = *reinterpret_cast<const short8*>(&As_lo[(chA + i * 16) * 8]);
        }
        #pragma unroll
        for (int j = 0; j < 4; j++) {
            b_hi[j] = *reinterpret_cast<const short8*>(&Ws_hi[(chB + j * 16) * 8]);
            b_lo[j] = *reinterpret_cast<const short8*>(&Ws_lo[(chB + j * 16) * 8]);
        }
        #pragma unroll
        for (int i = 0; i < 4; i++)
            #pragma unroll
            for (int j = 0; j < 4; j++) {
                acc[i][j] = __builtin_amdgcn_mfma_f32_16x16x32_bf16(a_hi[i], b_hi[j], acc[i][j], 0, 0, 0);
                acc[i][j] = __builtin_amdgcn_mfma_f32_16x16x32_bf16(a_hi[i], b_lo[j], acc[i][j], 0, 0, 0);
                acc[i][j] = __builtin_amdgcn_mfma_f32_16x16x32_bf16(a_lo[i], b_hi[j], acc[i][j], 0, 0, 0);
            }
        __syncthreads();
    }

    #pragma unroll
    for (int i = 0; i < 4; i++) {
        const int grow = row0 + wr * 64 + i * 16 + lg * 4;
        #pragma unroll
        for (int j = 0; j < 4; j++) {
            const int gcol = col0 + wc * 64 + j * 16 + lm;
            float bv = 0.f;
            if constexpr (ACT >= 1) bv = bias[gcol];
            #pragma unroll
            for (int r = 0; r < 4; r++)
                C[(size_t)(grow + r) * ldc + gcol] = acc[i][j][r] + bv;
        }
    }
}

// ---------------------------------------------------------------------------
// x_proj split-K MFMA: M=8192, N=64, K=1024 split into 8 parts of 128.
// grid = (128 M-tiles, 8 k-parts). Writes partials P[kp][8192][64].
// ---------------------------------------------------------------------------
__global__ __launch_bounds__(256)
void gemm_mfma_xp(const float* __restrict__ A,          // xi, lda=1024
                  const ushort* __restrict__ Whi,       // [64][1024]
                  const ushort* __restrict__ Wlo,
                  float* __restrict__ P)                // [8][8192][64]
{
    __shared__ short As_hi[2048], As_lo[2048], Ws_hi[2048], Ws_lo[2048]; // 16 KB

    const int tid  = threadIdx.x;
    const int lane = tid & 63;
    const int wave = tid >> 6;
    const int wr   = wave >> 1;
    const int wc   = wave & 1;
    const int row0 = blockIdx.x * 64;
    const int kp   = blockIdx.y;

    const int g = tid & 3;
    const int r = tid >> 2;      // 0..63
    const int ch_st = g * 64 + (r ^ g);

    const int lg = lane >> 4;
    const int lm = lane & 15;

    f32x4 acc[2][2];
    #pragma unroll
    for (int i = 0; i < 2; i++)
        #pragma unroll
        for (int j = 0; j < 2; j++) acc[i][j] = (f32x4){0.f, 0.f, 0.f, 0.f};

    for (int ks = 0; ks < 4; ks++) {
        const int kbase = kp * 128 + ks * 32;
        __syncthreads();
        {
            const float* ap = A + (size_t)(row0 + r) * 1024 + kbase + g * 8;
            const float4 v0 = *reinterpret_cast<const float4*>(ap);
            const float4 v1 = *reinterpret_cast<const float4*>(ap + 4);
            ushort h[8], l[8];
            cvt4(v0, h, l);
            cvt4(v1, h + 4, l + 4);
            short8 h8, l8;
            #pragma unroll
            for (int e = 0; e < 8; e++) { h8[e] = (short)h[e]; l8[e] = (short)l[e]; }
            *reinterpret_cast<short8*>(&As_hi[ch_st * 8]) = h8;
            *reinterpret_cast<short8*>(&As_lo[ch_st * 8]) = l8;
        }
        {
            const size_t wo = (size_t)r * 1024 + kbase + g * 8;
            *reinterpret_cast<short8*>(&Ws_hi[ch_st * 8]) =
                *reinterpret_cast<const short8*>(&Whi[wo]);
            *reinterpret_cast<short8*>(&Ws_lo[ch_st * 8]) =
                *reinterpret_cast<const short8*>(&Wlo[wo]);
        }
        __syncthreads();

        short8 a_hi[2], a_lo[2], b_hi[2], b_lo[2];
        #pragma unroll
        for (int i = 0; i < 2; i++) {
            const int ch = lg * 64 + ((wr * 32 + i * 16 + lm) ^ lg);
            a_hi[i] = *reinterpret_cast<const short8*>(&As_hi[ch * 8]);
            a_lo[i] = *reinterpret_cast<const short8*>(&As_lo[ch * 8]);
        }
        #pragma unroll
        for (int j = 0; j < 2; j++) {
            const int ch = lg * 64 + ((wc * 32 + j * 16 + lm) ^ lg);
            b_hi[j] = *reinterpret_cast<const short8*>(&Ws_hi[ch * 8]);
            b_lo[j] = *reinterpret_cast<const short8*>(&Ws_lo[ch * 8]);
        }
        #pragma unroll
        for (int i = 0; i < 2; i++)
            #pragma unroll
            for (int j = 0; j < 2; j++) {
                acc[i][j] = __builtin_amdgcn_mfma_f32_16x16x32_bf16(a_hi[i], b_hi[j], acc[i][j], 0, 0, 0);
                acc[i][j] = __builtin_amdgcn_mfma_f32_16x16x32_bf16(a_hi[i], b_lo[j], acc[i][j], 0, 0, 0);
                acc[i][j] = __builtin_amdgcn_mfma_f32_16x16x32_bf16(a_lo[i], b_hi[j], acc[i][j], 0, 0, 0);
            }
    }

    #pragma unroll
    for (int i = 0; i < 2; i++) {
        const int grow = row0 + wr * 32 + i * 16 + lg * 4;
        #pragma unroll
        for (int j = 0; j < 2; j++) {
            const int gcol = wc * 32 + j * 16 + lm;
            #pragma unroll
            for (int rr = 0; rr < 4; rr++)
                P[((size_t)kp * 8192 + grow + rr) * 64 + gcol] = acc[i][j][rr];
        }
    }
}

// Deterministic fixed-order reduction of the 8 k-part partials -> dbl.
__global__ __launch_bounds__(256)
void xp_reduce(const float* __restrict__ P, float* __restrict__ dbl)
{
    const int idx = blockIdx.x * 256 + threadIdx.x;   // 524288
    float s = 0.f;
    #pragma unroll
    for (int p = 0; p < 8; p++) s += P[(size_t)p * 524288 + idx];
    dbl[idx] = s;
}

// ---------------------------------------------------------------------------
// Causal depthwise conv (width 4) + SiLU.
// ---------------------------------------------------------------------------
__global__ __launch_bounds__(256)
void conv_silu_kernel(const float* __restrict__ xz,
                      const float* __restrict__ cw,   // (1024, 4)
                      const float* __restrict__ cb,   // (1024)
                      float* __restrict__ xi)
{
    const int idx = blockIdx.x * 256 + threadIdx.x;   // over 8*1024*1024
    const int d = idx & 1023;
    const int l = (idx >> 10) & 1023;
    const int b = idx >> 20;

    const float4 w = reinterpret_cast<const float4*>(cw)[d];
    float acc = cb[d];
    const float* base = xz + (size_t)b * 1024 * 2048 + d;
    if (l >= 3) acc = fmaf(base[(size_t)(l - 3) * 2048], w.x, acc);
    if (l >= 2) acc = fmaf(base[(size_t)(l - 2) * 2048], w.y, acc);
    if (l >= 1) acc = fmaf(base[(size_t)(l - 1) * 2048], w.z, acc);
    acc = fmaf(base[(size_t)l * 2048], w.w, acc);
    xi[idx] = siluf_(acc);
}

// ---------------------------------------------------------------------------
// Chunked selective scan. Phase 1: local scan (h0=0), dt computed inline
// (dt_proj fused) and STORED for phase 3. PF=8 double-buffered xi prefetch.
// grid = (4, NC, 8), block = 256.
// ---------------------------------------------------------------------------
__global__ __launch_bounds__(256)
void scan_p1(const float* __restrict__ xi,    // (B,L,1024)
             const float* __restrict__ dbl,   // (B,L,64): 0..31 dt-rank, 32..47 B
             const float* __restrict__ A_log, // (1024,16)
             const float* __restrict__ dtw,   // (1024,32)
             const float* __restrict__ dtb,   // (1024)
             float* __restrict__ hend,        // (B,NC,1024,16)
             float* __restrict__ dtsum,       // (B,NC,1024)
             float* __restrict__ dtout)       // (B,L,1024)
{
    __shared__ float S[LC][64];   // 8 KB: full dbl rows for this chunk
    const int tid = threadIdx.x;
    const int d   = blockIdx.x * 256 + tid;
    const int c   = blockIdx.y;
    const int b   = blockIdx.z;
    const int t0  = c * LC;

    // stage: LC*16 = 512 float4 units, 2 per thread
    #pragma unroll
    for (int u = 0; u < 2; u++) {
        const int unit = tid + u * 256;
        const int t = unit >> 4, q = unit & 15;
        *reinterpret_cast<float4*>(&S[t][q * 4]) =
            *reinterpret_cast<const float4*>(&dbl[((size_t)b * 1024 + t0 + t) * 64 + q * 4]);
    }
    __syncthreads();

    float A[16], W[32];
    #pragma unroll
    for (int s = 0; s < 16; s++) A[s] = -__expf(A_log[d * 16 + s]);
    #pragma unroll
    for (int q = 0; q < 8; q++)
        *reinterpret_cast<float4*>(&W[q * 4]) =
            *reinterpret_cast<const float4*>(&dtw[(size_t)d * 32 + q * 4]);
    const float bias = dtb[d];

    float h[16];
    #pragma unroll
    for (int s = 0; s < 16; s++) h[s] = 0.f;
    float dts = 0.f;

    const float* xi_p = xi + ((size_t)b * 1024 + t0) * 1024 + d;
    float* dto = dtout + ((size_t)b * 1024 + t0) * 1024 + d;

    float xA[PF], xB[PF];
    #pragma unroll
    for (int j = 0; j < PF; j++) xA[j] = xi_p[(size_t)j * 1024];

    auto batch = [&](int bt, float (&cx)[PF], float (&nx)[PF], bool pre) {
        if (pre) {
            #pragma unroll
            for (int j = 0; j < PF; j++)
                nx[j] = xi_p[(size_t)((bt + 1) * PF + j) * 1024];
        }
        #pragma unroll
        for (int j = 0; j < PF; j++) {
            const int t = bt * PF + j;
            float dtr = bias;
            #pragma unroll
            for (int q = 0; q < 8; q++) {
                const float4 sv = *reinterpret_cast<const float4*>(&S[t][q * 4]);
                dtr = fmaf(W[q * 4 + 0], sv.x, dtr);
                dtr = fmaf(W[q * 4 + 1], sv.y, dtr);
                dtr = fmaf(W[q * 4 + 2], sv.z, dtr);
                dtr = fmaf(W[q * 4 + 3], sv.w, dtr);
            }
            const float dtv = softplusf_(dtr);
            dto[(size_t)t * 1024] = dtv;
            dts += dtv;
            const float dx = dtv * cx[j];
            #pragma unroll
            for (int q = 0; q < 4; q++) {
                const float4 Bv = *reinterpret_cast<const float4*>(&S[t][32 + q * 4]);
                h[q*4+0] = fmaf(__expf(dtv * A[q*4+0]), h[q*4+0], dx * Bv.x);
                h[q*4+1] = fmaf(__expf(dtv * A[q*4+1]), h[q*4+1], dx * Bv.y);
                h[q*4+2] = fmaf(__expf(dtv * A[q*4+2]), h[q*4+2], dx * Bv.z);
                h[q*4+3] = fmaf(__expf(dtv * A[q*4+3]), h[q*4+3], dx * Bv.w);
            }
        }
    };
    batch(0, xA, xB, true);
    batch(1, xB, xA, true);
    batch(2, xA, xB, true);
    batch(3, xB, xA, false);

    float* hp = hend + (((size_t)b * NC + c) * 1024 + d) * 16;
    #pragma unroll
    for (int s = 0; s < 16; s += 4)
        *reinterpret_cast<float4*>(&hp[s]) = *reinterpret_cast<const float4*>(&h[s]);
    dtsum[((size_t)b * NC + c) * 1024 + d] = dts;
}

// Phase 2: scan over chunk summaries (NC steps).
__global__ __launch_bounds__(256)
void scan_p2(float* __restrict__ hbuf,
             const float* __restrict__ dtsum,
             const float* __restrict__ A_log)
{
    const int gid = blockIdx.x * 256 + threadIdx.x;  // 8*1024*16
    const int s = gid & 15;
    const int d = (gid >> 4) & 1023;
    const int b = gid >> 14;

    const float A = -__expf(A_log[d * 16 + s]);
    float h = 0.f;
    #pragma unroll
    for (int c = 0; c < NC; c++) {
        const size_t idx = (((size_t)b * NC + c) * 1024 + d) * 16 + s;
        const float he = hbuf[idx];
        const float aP = __expf(A * dtsum[((size_t)b * NC + c) * 1024 + d]);
        hbuf[idx] = h;
        h = fmaf(aP, h, he);
    }
}

// Phase 3: re-scan from true h0; dt read from p1's output; fuse
// y = h.C + x*D and silu(z) gating. PF=8 triple-stream prefetch (xi, z, dt).
__global__ __launch_bounds__(256)
void scan_p3(const float* __restrict__ xi,
             const float* __restrict__ dbl,   // cols 32..47 B, 48..63 C
             float* __restrict__ xz,          // read z (cols 1024..2047), write y
             const float* __restrict__ A_log,
             const float* __restrict__ Dp,
             const float* __restrict__ h0,    // (B,NC,1024,16)
             const float* __restrict__ dtin)  // (B,L,1024)
{
    __shared__ float S[LC][32];   // 4 KB: B,C halves only
    const int tid = threadIdx.x;
    const int d   = blockIdx.x * 256 + tid;
    const int c   = blockIdx.y;
    const int b   = blockIdx.z;
    const int t0  = c * LC;

    // stage: LC*8 = 256 float4 units, 1 per thread
    {
        const int t = tid >> 3, q = tid & 7;
        *reinterpret_cast<float4*>(&S[t][q * 4]) =
            *reinterpret_cast<const float4*>(&dbl[((size_t)b * 1024 + t0 + t) * 64 + 32 + q * 4]);
    }
    __syncthreads();

    float A[16], h[16];
    #pragma unroll
    for (int s = 0; s < 16; s++) A[s] = -__expf(A_log[d * 16 + s]);
    const float* h0p = h0 + (((size_t)b * NC + c) * 1024 + d) * 16;
    #pragma unroll
    for (int s = 0; s < 16; s += 4)
        *reinterpret_cast<float4*>(&h[s]) = *reinterpret_cast<const float4*>(&h0p[s]);

    const float Dv = Dp[d];
    const float* xi_p = xi   + ((size_t)b * 1024 + t0) * 1024 + d;
    const float* dt_p = dtin + ((size_t)b * 1024 + t0) * 1024 + d;
    const float* z_p  = xz   + ((size_t)b * 1024 + t0) * 2048 + 1024 + d;
    float*       y_p  = xz   + ((size_t)b * 1024 + t0) * 2048 + d;

    float xA[PF], xB[PF], zA[PF], zB[PF], dA[PF], dB[PF];
    #pragma unroll
    for (int j = 0; j < PF; j++) {
        xA[j] = xi_p[(size_t)j * 1024];
        zA[j] = z_p[(size_t)j * 2048];
        dA[j] = dt_p[(size_t)j * 1024];
    }

    auto batch = [&](int bt, float (&cx)[PF], float (&cz)[PF], float (&cd)[PF],
                     float (&nx)[PF], float (&nz)[PF], float (&nd)[PF], bool pre) {
        if (pre) {
            #pragma unroll
            for (int j = 0; j < PF; j++) {
                const size_t tt = (size_t)((bt + 1) * PF + j);
                nx[j] = xi_p[tt * 1024];
                nz[j] = z_p[tt * 2048];
                nd[j] = dt_p[tt * 1024];
            }
        }
        #pragma unroll
        for (int j = 0; j < PF; j++) {
            const int t = bt * PF + j;
            const float dtv = cd[j];
            const float dx  = dtv * cx[j];
            float y = 0.f;
            #pragma unroll
            for (int q = 0; q < 4; q++) {
                const float4 Bv = *reinterpret_cast<const float4*>(&S[t][q * 4]);
                const float4 Cv = *reinterpret_cast<const float4*>(&S[t][16 + q * 4]);
                h[q*4+0] = fmaf(__expf(dtv * A[q*4+0]), h[q*4+0], dx * Bv.x);
                h[q*4+1] = fmaf(__expf(dtv * A[q*4+1]), h[q*4+1], dx * Bv.y);
                h[q*4+2] = fmaf(__expf(dtv * A[q*4+2]), h[q*4+2], dx * Bv.z);
                h[q*4+3] = fmaf(__expf(dtv * A[q*4+3]), h[q*4+3], dx * Bv.w);
                y = fmaf(h[q*4+0], Cv.x, y);
                y = fmaf(h[q*4+1], Cv.y, y);
                y = fmaf(h[q*4+2], Cv.z, y);
                y = fmaf(h[q*4+3], Cv.w, y);
            }
            y_p[(size_t)t * 2048] = (y + cx[j] * Dv) * siluf_(cz[j]);
        }
    };
    batch(0, xA, zA, dA, xB, zB, dB, true);
    batch(1, xB, zB, dB, xA, zA, dA, true);
    batch(2, xA, zA, dA, xB, zB, dB, true);
    batch(3, xB, zB, dB, xA, zA, dA, false);
}

// ---------------------------------------------------------------------------
// Heads
// ---------------------------------------------------------------------------
__global__ __launch_bounds__(256)
void head1_kernel(const float* __restrict__ x,
                  const float* __restrict__ w,
                  const float* __restrict__ bias,
                  float* __restrict__ hh)
{
    const int tid = threadIdx.x;
    const int jl  = tid >> 4;
    const int ks  = tid & 15;
    const int j   = blockIdx.x * 16 + jl;

    const float* wr = w + (size_t)j * 512 + ks * 32;
    float acc[8];
    #pragma unroll
    for (int b = 0; b < 8; b++) {
        const float* xr = x + ((size_t)b * 1024 + 1023) * 512 + ks * 32;
        float a = 0.f;
        #pragma unroll
        for (int k = 0; k < 32; k += 4) {
            const float4 wv = *reinterpret_cast<const float4*>(&wr[k]);
            const float4 xv = *reinterpret_cast<const float4*>(&xr[k]);
            a = fmaf(wv.x, xv.x, a); a = fmaf(wv.y, xv.y, a);
            a = fmaf(wv.z, xv.z, a); a = fmaf(wv.w, xv.w, a);
        }
        acc[b] = a;
    }
    #pragma unroll
    for (int b = 0; b < 8; b++) {
        float p = acc[b];
        p += __shfl_xor(p, 1);
        p += __shfl_xor(p, 2);
        p += __shfl_xor(p, 4);
        p += __shfl_xor(p, 8);
        if (ks == 0) hh[b * 256 + j] = fmaxf(p + bias[j], 0.f);
    }
}

__global__ void head2_kernel(const float* __restrict__ hh,
                             const float* __restrict__ w,
                             const float* __restrict__ b2,
                             float* __restrict__ out)
{
    const int t = threadIdx.x;
    if (t < 72) {
        const int bb = t / 9, a = t % 9;
        const float* hr = hh + bb * 256;
        const float* wr = w + a * 256;
        float acc = b2[a];
        for (int jj = 0; jj < 256; jj++) acc = fmaf(hr[jj], wr[jj], acc);
        out[t] = acc;
    }
}

// ---------------------------------------------------------------------------

extern "C" void kernel_launch(void* const* d_in, const int* in_sizes, int n_in,
                              void* d_out, int out_size, void* d_ws, size_t ws_size,
                              hipStream_t stream)
{
    const float* state     = (const float*)d_in[0];
    const float* embed_w   = (const float*)d_in[1];
    const float* embed_b   = (const float*)d_in[2];
    const float* in_proj_w = (const float*)d_in[3];
    const float* conv_w    = (const float*)d_in[4];
    const float* conv_b    = (const float*)d_in[5];
    const float* x_proj_w  = (const float*)d_in[6];
    const float* dt_proj_w = (const float*)d_in[7];
    const float* dt_proj_b = (const float*)d_in[8];
    const float* A_log     = (const float*)d_in[9];
    const float* Dp        = (const float*)d_in[10];
    const float* out_proj_w= (const float*)d_in[11];
    const float* h1w       = (const float*)d_in[12];
    const float* h1b       = (const float*)d_in[13];
    const float* h2w       = (const float*)d_in[14];
    const float* h2b       = (const float*)d_in[15];
    float* out = (float*)d_out;

    // fp32 workspace
    float* x    = (float*)d_ws;                   // 8192*512 = 4,194,304
    float* xz   = x    + (size_t)8192 * 512;      // 8192*2048
    float* xi   = xz   + (size_t)8192 * 2048;     // 8192*1024
    float* dtbf = xi   + (size_t)8192 * 1024;     // 8192*1024  (dt values)
    float* dbl  = dtbf + (size_t)8192 * 1024;     // 8192*64
    float* hh   = dbl  + (size_t)8192 * 64;       // 2048
    // bf16 hi/lo weight planes (ushort)
    ushort* wl = (ushort*)(hh + 2048);            // 3,276,800 ushorts
    ushort* we_hi = wl + 3276800;                 // embed: 131072 + 131072
    ushort* we_lo = we_hi + 131072;
    float* dtsum = (float*)(we_lo + 131072);      // B*NC*1024 = 262,144 floats

    // x region is dead between in_proj and out_proj: xp partials (4.19M,
    // exact fit), then hbuf (B*NC*1024*16 = 4.19M, exact fit).
    float* dblp = x;
    float* hbuf = x;

    const dim3 blk(256);

    // embed weights -> bf16 hi/lo, then embed GEMM (M=8192,N=512,K=256)
    wcvt_kernel<<<dim3(128), blk, 0, stream>>>(embed_w, we_hi, we_lo, 131072 / 4);
    gemm_mfma<1><<<dim3(4, 64), blk, 0, stream>>>(
        state, 256, we_hi, we_lo, 256, embed_b, x, 512, 256);

    for (int i = 0; i < 3; i++) {
        const float* Alog_i = A_log + (size_t)i * 1024 * 16;
        const float* dtw_i  = dt_proj_w + (size_t)i * 1024 * 32;
        const float* dtb_i  = dt_proj_b + (size_t)i * 1024;

        // convert this layer's weights (in/out/xp)
        wcvt3_kernel<<<dim3(1600), blk, 0, stream>>>(
            in_proj_w + (size_t)i * 2048 * 512,
            out_proj_w + (size_t)i * 512 * 1024,
            x_proj_w + (size_t)i * 64 * 1024, wl);

        // in_proj: xz = x @ in_w^T  (N=2048, K=512)
        gemm_mfma<0><<<dim3(16, 64), blk, 0, stream>>>(
            x, 512, wl, wl + 1048576, 512, nullptr, xz, 2048, 512);

        // causal depthwise conv + silu -> xi
        conv_silu_kernel<<<dim3(8 * 1024 * 1024 / 256), blk, 0, stream>>>(
            xz, conv_w + (size_t)i * 1024 * 4, conv_b + (size_t)i * 1024, xi);

        // x_proj: dbl = xi @ xw^T  (N=64, K=1024) — split-K MFMA + reduce
        gemm_mfma_xp<<<dim3(128, 8), blk, 0, stream>>>(
            xi, wl + 3145728, wl + 3211264, dblp);
        xp_reduce<<<dim3(2048), blk, 0, stream>>>(dblp, dbl);

        // chunked selective scan, dt fused in p1 and stored for p3
        scan_p1<<<dim3(4, NC, 8), blk, 0, stream>>>(
            xi, dbl, Alog_i, dtw_i, dtb_i, hbuf, dtsum, dtbf);
        scan_p2<<<dim3(512), blk, 0, stream>>>(hbuf, dtsum, Alog_i);
        scan_p3<<<dim3(4, NC, 8), blk, 0, stream>>>(
            xi, dbl, xz, Alog_i, Dp + (size_t)i * 1024, hbuf, dtbf);

        // out_proj: x = y @ ow^T  (N=512, K=1024; A = xz with lda=2048)
        gemm_mfma<0><<<dim3(4, 64), blk, 0, stream>>>(
            xz, 2048, wl + 2097152, wl + 2621440, 1024, nullptr, x, 512, 1024);
    }

    head1_kernel<<<dim3(16), blk, 0, stream>>>(x, h1w, h1b, hh);
    head2_kernel<<<dim3(1), dim3(128), 0, stream>>>(hh, h2w, h2b, out);
}

// Round 7
// 834.873 us; speedup vs baseline: 1.1252x; 1.1252x over previous
//
#include <hip/hip_runtime.h>
#include <cstdint>
#include <cstddef>

// ---------------------------------------------------------------------------
// Mamba BC network forward.
//  - Split-precision bf16 MFMA GEMMs (hi/lo 3-pass) with 2-phase reg prefetch
//  - dedicated lean dt kernel (dt_proj+softplus, LDS-staged dbl, W in regs)
//  - minimal chunked selective scan (LC=32): p1 h-recurrence only, p3 +y/gate
// B=8, L=1024, D_MODEL=512, D_INNER=1024, D_STATE=16, D_CONV=4, DT_RANK=32, 3 layers.
// ---------------------------------------------------------------------------

#define DEVI static __device__ __forceinline__

using short8 = __attribute__((ext_vector_type(8))) short;
using f32x4  = __attribute__((ext_vector_type(4))) float;
typedef unsigned short ushort;
typedef unsigned int uint;

DEVI float sigmoidf_(float x) { return 1.f / (1.f + __expf(-x)); }
DEVI float siluf_(float x)    { return x * sigmoidf_(x); }
DEVI float softplusf_(float x){ return fmaxf(x, 0.f) + log1pf(expf(-fabsf(x))); }

DEVI ushort rne_bf16(float f) {
    uint u = __float_as_uint(f);
    return (ushort)((u + 0x7fffu + ((u >> 16) & 1u)) >> 16);
}
DEVI float bf16_to_f(ushort h) { return __uint_as_float(((uint)h) << 16); }

constexpr int LC = 32;   // scan chunk length
constexpr int NC = 32;   // number of chunks (1024 / 32)
constexpr int PF = 8;    // prefetch batch

// ---------------------------------------------------------------------------
// Weight conversion: fp32 -> bf16 hi plane + bf16 lo plane (lo = x - hi).
// ---------------------------------------------------------------------------
DEVI void cvt4(const float4 v, ushort* h, ushort* l) {
    const float vv[4] = {v.x, v.y, v.z, v.w};
    #pragma unroll
    for (int e = 0; e < 4; e++) {
        const ushort hh = rne_bf16(vv[e]);
        h[e] = hh;
        l[e] = rne_bf16(vv[e] - bf16_to_f(hh));
    }
}

__global__ __launch_bounds__(256)
void wcvt_kernel(const float* __restrict__ src, ushort* __restrict__ hi,
                 ushort* __restrict__ lo, int n4)
{
    const int idx = blockIdx.x * 256 + threadIdx.x;
    if (idx >= n4) return;
    const float4 v = reinterpret_cast<const float4*>(src)[idx];
    ushort h[4], l[4];
    cvt4(v, h, l);
    *reinterpret_cast<ushort4*>(&hi[idx * 4]) = make_ushort4(h[0], h[1], h[2], h[3]);
    *reinterpret_cast<ushort4*>(&lo[idx * 4]) = make_ushort4(l[0], l[1], l[2], l[3]);
}

// Converts one layer's in_proj (1048576), out_proj (524288), x_proj (65536)
// weights into packed hi/lo planes inside dst (ushort offsets):
// in_hi 0 | in_lo 1048576 | out_hi 2097152 | out_lo 2621440 |
// xp_hi 3145728 | xp_lo 3211264   (total 3276800 ushorts)
__global__ __launch_bounds__(256)
void wcvt3_kernel(const float* __restrict__ s_in, const float* __restrict__ s_out,
                  const float* __restrict__ s_xp, ushort* __restrict__ dst)
{
    const int idx = blockIdx.x * 256 + threadIdx.x;   // 409600 float4 units
    if (idx >= 409600) return;
    const int e0 = idx * 4;
    const float* src; ushort* hb; ushort* lb; int loc;
    if (e0 < 1048576)      { src = s_in;  hb = dst;           lb = dst + 1048576; loc = e0; }
    else if (e0 < 1572864) { src = s_out; hb = dst + 2097152; lb = dst + 2621440; loc = e0 - 1048576; }
    else                   { src = s_xp;  hb = dst + 3145728; lb = dst + 3211264; loc = e0 - 1572864; }
    const float4 v = *reinterpret_cast<const float4*>(&src[loc]);
    ushort h[4], l[4];
    cvt4(v, h, l);
    *reinterpret_cast<ushort4*>(&hb[loc]) = make_ushort4(h[0], h[1], h[2], h[3]);
    *reinterpret_cast<ushort4*>(&lb[loc]) = make_ushort4(l[0], l[1], l[2], l[3]);
}

// ---------------------------------------------------------------------------
// Split-precision bf16 MFMA GEMM with 2-phase register prefetch:
// C[m,n] = sum_k A[m,k]*W[n,k] (+bias). 128x128 tile, BK=32, 4 waves (2x2).
// ACT: 0 none, 1 +bias.
// ---------------------------------------------------------------------------
template<int ACT>
__global__ __launch_bounds__(256)
void gemm_mfma(const float* __restrict__ A, int lda,
               const ushort* __restrict__ Whi, const ushort* __restrict__ Wlo,
               int ldw, const float* __restrict__ bias,
               float* __restrict__ C, int ldc, int K)
{
    __shared__ short As_hi[4096], As_lo[4096], Ws_hi[4096], Ws_lo[4096]; // 32 KB

    const int tid  = threadIdx.x;
    const int lane = tid & 63;
    const int wave = tid >> 6;
    const int wr   = wave >> 1;
    const int wc   = wave & 1;
    const int row0 = blockIdx.y * 128;
    const int col0 = blockIdx.x * 128;

    const int g  = tid & 3;
    const int r0 = tid >> 2;

    const int lg = lane >> 4;
    const int lm = lane & 15;
    const int chA = lg * 128 + ((wr * 64 + lm) ^ lg);
    const int chB = lg * 128 + ((wc * 64 + lm) ^ lg);

    f32x4 acc[4][4];
    #pragma unroll
    for (int i = 0; i < 4; i++)
        #pragma unroll
        for (int j = 0; j < 4; j++) acc[i][j] = (f32x4){0.f, 0.f, 0.f, 0.f};

    float4 av0[2], av1[2];
    short8 wh[2], wl8[2];

    auto gload = [&](int k0) {
        #pragma unroll
        for (int p = 0; p < 2; p++) {
            const int rr = r0 + p * 64;
            const float* ap = A + (size_t)(row0 + rr) * lda + k0 + g * 8;
            av0[p] = *reinterpret_cast<const float4*>(ap);
            av1[p] = *reinterpret_cast<const float4*>(ap + 4);
            const size_t wo = (size_t)(col0 + rr) * ldw + k0 + g * 8;
            wh[p]  = *reinterpret_cast<const short8*>(&Whi[wo]);
            wl8[p] = *reinterpret_cast<const short8*>(&Wlo[wo]);
        }
    };

    gload(0);

    for (int k0 = 0; k0 < K; k0 += 32) {
        #pragma unroll
        for (int p = 0; p < 2; p++) {
            const int ch = g * 128 + ((r0 + p * 64) ^ g);
            ushort h[8], l[8];
            cvt4(av0[p], h, l);
            cvt4(av1[p], h + 4, l + 4);
            short8 h8, l8;
            #pragma unroll
            for (int e = 0; e < 8; e++) { h8[e] = (short)h[e]; l8[e] = (short)l[e]; }
            *reinterpret_cast<short8*>(&As_hi[ch * 8]) = h8;
            *reinterpret_cast<short8*>(&As_lo[ch * 8]) = l8;
            *reinterpret_cast<short8*>(&Ws_hi[ch * 8]) = wh[p];
            *reinterpret_cast<short8*>(&Ws_lo[ch * 8]) = wl8[p];
        }
        if (k0 + 32 < K) gload(k0 + 32);   // in flight during barrier+MFMA
        __syncthreads();

        short8 a_hi[4], a_lo[4], b_hi[4], b_lo[4];
        #pragma unroll
        for (int i = 0; i < 4; i++) {
            a_hi[i] = *reinterpret_cast<const short8*>(&As_hi[(chA + i * 16) * 8]);
            a_lo[i] = *reinterpret_cast<const short8*>(&As_lo[(chA + i * 16) * 8]);
        }
        #pragma unroll
        for (int j = 0; j < 4; j++) {
            b_hi[j] = *reinterpret_cast<const short8*>(&Ws_hi[(chB + j * 16) * 8]);
            b_lo[j] = *reinterpret_cast<const short8*>(&Ws_lo[(chB + j * 16) * 8]);
        }
        #pragma unroll
        for (int i = 0; i < 4; i++)
            #pragma unroll
            for (int j = 0; j < 4; j++) {
                acc[i][j] = __builtin_amdgcn_mfma_f32_16x16x32_bf16(a_hi[i], b_hi[j], acc[i][j], 0, 0, 0);
                acc[i][j] = __builtin_amdgcn_mfma_f32_16x16x32_bf16(a_hi[i], b_lo[j], acc[i][j], 0, 0, 0);
                acc[i][j] = __builtin_amdgcn_mfma_f32_16x16x32_bf16(a_lo[i], b_hi[j], acc[i][j], 0, 0, 0);
            }
        __syncthreads();
    }

    #pragma unroll
    for (int i = 0; i < 4; i++) {
        const int grow = row0 + wr * 64 + i * 16 + lg * 4;
        #pragma unroll
        for (int j = 0; j < 4; j++) {
            const int gcol = col0 + wc * 64 + j * 16 + lm;
            float bv = 0.f;
            if constexpr (ACT >= 1) bv = bias[gcol];
            #pragma unroll
            for (int r = 0; r < 4; r++)
                C[(size_t)(grow + r) * ldc + gcol] = acc[i][j][r] + bv;
        }
    }
}

// ---------------------------------------------------------------------------
// x_proj split-K MFMA: M=8192, N=64, K=1024 split into 8 parts of 128.
// grid = (128 M-tiles, 8 k-parts). Writes partials P[kp][8192][64].
// ---------------------------------------------------------------------------
__global__ __launch_bounds__(256)
void gemm_mfma_xp(const float* __restrict__ A,          // xi, lda=1024
                  const ushort* __restrict__ Whi,       // [64][1024]
                  const ushort* __restrict__ Wlo,
                  float* __restrict__ P)                // [8][8192][64]
{
    __shared__ short As_hi[2048], As_lo[2048], Ws_hi[2048], Ws_lo[2048]; // 16 KB

    const int tid  = threadIdx.x;
    const int lane = tid & 63;
    const int wave = tid >> 6;
    const int wr   = wave >> 1;
    const int wc   = wave & 1;
    const int row0 = blockIdx.x * 64;
    const int kp   = blockIdx.y;

    const int g = tid & 3;
    const int r = tid >> 2;      // 0..63
    const int ch_st = g * 64 + (r ^ g);

    const int lg = lane >> 4;
    const int lm = lane & 15;

    f32x4 acc[2][2];
    #pragma unroll
    for (int i = 0; i < 2; i++)
        #pragma unroll
        for (int j = 0; j < 2; j++) acc[i][j] = (f32x4){0.f, 0.f, 0.f, 0.f};

    for (int ks = 0; ks < 4; ks++) {
        const int kbase = kp * 128 + ks * 32;
        __syncthreads();
        {
            const float* ap = A + (size_t)(row0 + r) * 1024 + kbase + g * 8;
            const float4 v0 = *reinterpret_cast<const float4*>(ap);
            const float4 v1 = *reinterpret_cast<const float4*>(ap + 4);
            ushort h[8], l[8];
            cvt4(v0, h, l);
            cvt4(v1, h + 4, l + 4);
            short8 h8, l8;
            #pragma unroll
            for (int e = 0; e < 8; e++) { h8[e] = (short)h[e]; l8[e] = (short)l[e]; }
            *reinterpret_cast<short8*>(&As_hi[ch_st * 8]) = h8;
            *reinterpret_cast<short8*>(&As_lo[ch_st * 8]) = l8;
        }
        {
            const size_t wo = (size_t)r * 1024 + kbase + g * 8;
            *reinterpret_cast<short8*>(&Ws_hi[ch_st * 8]) =
                *reinterpret_cast<const short8*>(&Whi[wo]);
            *reinterpret_cast<short8*>(&Ws_lo[ch_st * 8]) =
                *reinterpret_cast<const short8*>(&Wlo[wo]);
        }
        __syncthreads();

        short8 a_hi[2], a_lo[2], b_hi[2], b_lo[2];
        #pragma unroll
        for (int i = 0; i < 2; i++) {
            const int ch = lg * 64 + ((wr * 32 + i * 16 + lm) ^ lg);
            a_hi[i] = *reinterpret_cast<const short8*>(&As_hi[ch * 8]);
            a_lo[i] = *reinterpret_cast<const short8*>(&As_lo[ch * 8]);
        }
        #pragma unroll
        for (int j = 0; j < 2; j++) {
            const int ch = lg * 64 + ((wc * 32 + j * 16 + lm) ^ lg);
            b_hi[j] = *reinterpret_cast<const short8*>(&Ws_hi[ch * 8]);
            b_lo[j] = *reinterpret_cast<const short8*>(&Ws_lo[ch * 8]);
        }
        #pragma unroll
        for (int i = 0; i < 2; i++)
            #pragma unroll
            for (int j = 0; j < 2; j++) {
                acc[i][j] = __builtin_amdgcn_mfma_f32_16x16x32_bf16(a_hi[i], b_hi[j], acc[i][j], 0, 0, 0);
                acc[i][j] = __builtin_amdgcn_mfma_f32_16x16x32_bf16(a_hi[i], b_lo[j], acc[i][j], 0, 0, 0);
                acc[i][j] = __builtin_amdgcn_mfma_f32_16x16x32_bf16(a_lo[i], b_hi[j], acc[i][j], 0, 0, 0);
            }
    }

    #pragma unroll
    for (int i = 0; i < 2; i++) {
        const int grow = row0 + wr * 32 + i * 16 + lg * 4;
        #pragma unroll
        for (int j = 0; j < 2; j++) {
            const int gcol = wc * 32 + j * 16 + lm;
            #pragma unroll
            for (int rr = 0; rr < 4; rr++)
                P[((size_t)kp * 8192 + grow + rr) * 64 + gcol] = acc[i][j][rr];
        }
    }
}

// Deterministic fixed-order reduction of the 8 k-part partials -> dbl.
__global__ __launch_bounds__(256)
void xp_reduce(const float* __restrict__ P, float* __restrict__ dbl)
{
    const int idx = blockIdx.x * 256 + threadIdx.x;   // 524288
    float s = 0.f;
    #pragma unroll
    for (int p = 0; p < 8; p++) s += P[(size_t)p * 524288 + idx];
    dbl[idx] = s;
}

// ---------------------------------------------------------------------------
// Causal depthwise conv (width 4) + SiLU.
// ---------------------------------------------------------------------------
__global__ __launch_bounds__(256)
void conv_silu_kernel(const float* __restrict__ xz,
                      const float* __restrict__ cw,   // (1024, 4)
                      const float* __restrict__ cb,   // (1024)
                      float* __restrict__ xi)
{
    const int idx = blockIdx.x * 256 + threadIdx.x;   // over 8*1024*1024
    const int d = idx & 1023;
    const int l = (idx >> 10) & 1023;
    const int b = idx >> 20;

    const float4 w = reinterpret_cast<const float4*>(cw)[d];
    float acc = cb[d];
    const float* base = xz + (size_t)b * 1024 * 2048 + d;
    if (l >= 3) acc = fmaf(base[(size_t)(l - 3) * 2048], w.x, acc);
    if (l >= 2) acc = fmaf(base[(size_t)(l - 2) * 2048], w.y, acc);
    if (l >= 1) acc = fmaf(base[(size_t)(l - 1) * 2048], w.z, acc);
    acc = fmaf(base[(size_t)l * 2048], w.w, acc);
    xi[idx] = siluf_(acc);
}

// ---------------------------------------------------------------------------
// Lean dt kernel: dt[b,t,d] = softplus(dtb[d] + sum_r dtw[d,r]*dbl[b,t,r]).
// grid = (4, 32, 8), block 256. dbl dt-rank cols staged in LDS; W[32] in regs.
// Compute ~0.55 GF, traffic 35 MB -> BW/VALU bound, no serial chains.
// ---------------------------------------------------------------------------
__global__ __launch_bounds__(256)
void dt_kernel(const float* __restrict__ dbl,   // (B,L,64), cols 0..31
               const float* __restrict__ dtw,   // (1024,32)
               const float* __restrict__ dtb,   // (1024)
               float* __restrict__ dtout)       // (B,L,1024)
{
    __shared__ float S[LC][32];   // 4 KB
    const int tid = threadIdx.x;
    const int d   = blockIdx.x * 256 + tid;
    const int c   = blockIdx.y;
    const int b   = blockIdx.z;
    const int t0  = c * LC;

    {   // LC*8 = 256 float4 units, 1 per thread
        const int t = tid >> 3, q = tid & 7;
        *reinterpret_cast<float4*>(&S[t][q * 4]) =
            *reinterpret_cast<const float4*>(&dbl[((size_t)b * 1024 + t0 + t) * 64 + q * 4]);
    }
    __syncthreads();

    float W[32];
    #pragma unroll
    for (int q = 0; q < 8; q++)
        *reinterpret_cast<float4*>(&W[q * 4]) =
            *reinterpret_cast<const float4*>(&dtw[(size_t)d * 32 + q * 4]);
    const float bias = dtb[d];

    float* dto = dtout + ((size_t)b * 1024 + t0) * 1024 + d;
    #pragma unroll 4
    for (int t = 0; t < LC; t++) {
        // 4 partial accumulators: short dependency chains
        float a0 = bias, a1 = 0.f, a2 = 0.f, a3 = 0.f;
        #pragma unroll
        for (int q = 0; q < 8; q += 4) {
            const float4 s0 = *reinterpret_cast<const float4*>(&S[t][q * 4]);
            const float4 s1 = *reinterpret_cast<const float4*>(&S[t][q * 4 + 4]);
            a0 = fmaf(W[q*4+0], s0.x, a0); a1 = fmaf(W[q*4+1], s0.y, a1);
            a2 = fmaf(W[q*4+2], s0.z, a2); a3 = fmaf(W[q*4+3], s0.w, a3);
            a0 = fmaf(W[q*4+4], s1.x, a0); a1 = fmaf(W[q*4+5], s1.y, a1);
            a2 = fmaf(W[q*4+6], s1.z, a2); a3 = fmaf(W[q*4+7], s1.w, a3);
        }
        dto[(size_t)t * 1024] = softplusf_((a0 + a1) + (a2 + a3));
    }
}

// ---------------------------------------------------------------------------
// Minimal chunked selective scan.
// Phase 1: local scan (h0=0) reading precomputed dt. Writes hend + dtsum only.
// ---------------------------------------------------------------------------
__global__ __launch_bounds__(256)
void scan_p1(const float* __restrict__ xi,    // (B,L,1024)
             const float* __restrict__ dtin,  // (B,L,1024)
             const float* __restrict__ dbl,   // (B,L,64): cols 32..47 = B
             const float* __restrict__ A_log, // (1024,16)
             float* __restrict__ hend,        // (B,NC,1024,16)
             float* __restrict__ dtsum)       // (B,NC,1024)
{
    __shared__ float S[LC][16];   // 2 KB: B cols
    const int tid = threadIdx.x;
    const int d   = blockIdx.x * 256 + tid;
    const int c   = blockIdx.y;
    const int b   = blockIdx.z;
    const int t0  = c * LC;

    if (tid < 128) {   // LC*4 = 128 float4 units
        const int t = tid >> 2, q = tid & 3;
        *reinterpret_cast<float4*>(&S[t][q * 4]) =
            *reinterpret_cast<const float4*>(&dbl[((size_t)b * 1024 + t0 + t) * 64 + 32 + q * 4]);
    }
    __syncthreads();

    float A[16], h[16];
    #pragma unroll
    for (int s = 0; s < 16; s++) A[s] = -__expf(A_log[d * 16 + s]);
    #pragma unroll
    for (int s = 0; s < 16; s++) h[s] = 0.f;
    float dts = 0.f;

    const float* xi_p = xi   + ((size_t)b * 1024 + t0) * 1024 + d;
    const float* dt_p = dtin + ((size_t)b * 1024 + t0) * 1024 + d;

    float xA[PF], xB[PF], dA[PF], dB[PF];
    #pragma unroll
    for (int j = 0; j < PF; j++) {
        xA[j] = xi_p[(size_t)j * 1024];
        dA[j] = dt_p[(size_t)j * 1024];
    }

    auto batch = [&](int bt, float (&cx)[PF], float (&cd)[PF],
                     float (&nx)[PF], float (&nd)[PF], bool pre) {
        if (pre) {
            #pragma unroll
            for (int j = 0; j < PF; j++) {
                const size_t tt = (size_t)((bt + 1) * PF + j);
                nx[j] = xi_p[tt * 1024];
                nd[j] = dt_p[tt * 1024];
            }
        }
        #pragma unroll
        for (int j = 0; j < PF; j++) {
            const int t = bt * PF + j;
            const float dtv = cd[j];
            dts += dtv;
            const float dx = dtv * cx[j];
            #pragma unroll
            for (int q = 0; q < 4; q++) {
                const float4 Bv = *reinterpret_cast<const float4*>(&S[t][q * 4]);
                h[q*4+0] = fmaf(__expf(dtv * A[q*4+0]), h[q*4+0], dx * Bv.x);
                h[q*4+1] = fmaf(__expf(dtv * A[q*4+1]), h[q*4+1], dx * Bv.y);
                h[q*4+2] = fmaf(__expf(dtv * A[q*4+2]), h[q*4+2], dx * Bv.z);
                h[q*4+3] = fmaf(__expf(dtv * A[q*4+3]), h[q*4+3], dx * Bv.w);
            }
        }
    };
    batch(0, xA, dA, xB, dB, true);
    batch(1, xB, dB, xA, dA, true);
    batch(2, xA, dA, xB, dB, true);
    batch(3, xB, dB, xA, dA, false);

    float* hp = hend + (((size_t)b * NC + c) * 1024 + d) * 16;
    #pragma unroll
    for (int s = 0; s < 16; s += 4)
        *reinterpret_cast<float4*>(&hp[s]) = *reinterpret_cast<const float4*>(&h[s]);
    dtsum[((size_t)b * NC + c) * 1024 + d] = dts;
}

// Phase 2: scan over chunk summaries (NC steps).
__global__ __launch_bounds__(256)
void scan_p2(float* __restrict__ hbuf,
             const float* __restrict__ dtsum,
             const float* __restrict__ A_log)
{
    const int gid = blockIdx.x * 256 + threadIdx.x;  // 8*1024*16
    const int s = gid & 15;
    const int d = (gid >> 4) & 1023;
    const int b = gid >> 14;

    const float A = -__expf(A_log[d * 16 + s]);
    float h = 0.f;
    #pragma unroll
    for (int c = 0; c < NC; c++) {
        const size_t idx = (((size_t)b * NC + c) * 1024 + d) * 16 + s;
        const float he = hbuf[idx];
        const float aP = __expf(A * dtsum[((size_t)b * NC + c) * 1024 + d]);
        hbuf[idx] = h;
        h = fmaf(aP, h, he);
    }
}

// Phase 3: re-scan from true h0; fuse y = h.C + x*D and silu(z) gating.
// PF=8 triple-stream prefetch (xi, z, dt).
__global__ __launch_bounds__(256)
void scan_p3(const float* __restrict__ xi,
             const float* __restrict__ dtin,  // (B,L,1024)
             const float* __restrict__ dbl,   // cols 32..47 B, 48..63 C
             float* __restrict__ xz,          // read z (cols 1024..2047), write y
             const float* __restrict__ A_log,
             const float* __restrict__ Dp,
             const float* __restrict__ h0)    // (B,NC,1024,16)
{
    __shared__ float S[LC][32];   // 4 KB: B,C halves
    const int tid = threadIdx.x;
    const int d   = blockIdx.x * 256 + tid;
    const int c   = blockIdx.y;
    const int b   = blockIdx.z;
    const int t0  = c * LC;

    {   // LC*8 = 256 float4 units, 1 per thread
        const int t = tid >> 3, q = tid & 7;
        *reinterpret_cast<float4*>(&S[t][q * 4]) =
            *reinterpret_cast<const float4*>(&dbl[((size_t)b * 1024 + t0 + t) * 64 + 32 + q * 4]);
    }
    __syncthreads();

    float A[16], h[16];
    #pragma unroll
    for (int s = 0; s < 16; s++) A[s] = -__expf(A_log[d * 16 + s]);
    const float* h0p = h0 + (((size_t)b * NC + c) * 1024 + d) * 16;
    #pragma unroll
    for (int s = 0; s < 16; s += 4)
        *reinterpret_cast<float4*>(&h[s]) = *reinterpret_cast<const float4*>(&h0p[s]);

    const float Dv = Dp[d];
    const float* xi_p = xi   + ((size_t)b * 1024 + t0) * 1024 + d;
    const float* dt_p = dtin + ((size_t)b * 1024 + t0) * 1024 + d;
    const float* z_p  = xz   + ((size_t)b * 1024 + t0) * 2048 + 1024 + d;
    float*       y_p  = xz   + ((size_t)b * 1024 + t0) * 2048 + d;

    float xA[PF], xB[PF], zA[PF], zB[PF], dA[PF], dB[PF];
    #pragma unroll
    for (int j = 0; j < PF; j++) {
        xA[j] = xi_p[(size_t)j * 1024];
        zA[j] = z_p[(size_t)j * 2048];
        dA[j] = dt_p[(size_t)j * 1024];
    }

    auto batch = [&](int bt, float (&cx)[PF], float (&cz)[PF], float (&cd)[PF],
                     float (&nx)[PF], float (&nz)[PF], float (&nd)[PF], bool pre) {
        if (pre) {
            #pragma unroll
            for (int j = 0; j < PF; j++) {
                const size_t tt = (size_t)((bt + 1) * PF + j);
                nx[j] = xi_p[tt * 1024];
                nz[j] = z_p[tt * 2048];
                nd[j] = dt_p[tt * 1024];
            }
        }
        #pragma unroll
        for (int j = 0; j < PF; j++) {
            const int t = bt * PF + j;
            const float dtv = cd[j];
            const float dx  = dtv * cx[j];
            float y = 0.f;
            #pragma unroll
            for (int q = 0; q < 4; q++) {
                const float4 Bv = *reinterpret_cast<const float4*>(&S[t][q * 4]);
                const float4 Cv = *reinterpret_cast<const float4*>(&S[t][16 + q * 4]);
                h[q*4+0] = fmaf(__expf(dtv * A[q*4+0]), h[q*4+0], dx * Bv.x);
                h[q*4+1] = fmaf(__expf(dtv * A[q*4+1]), h[q*4+1], dx * Bv.y);
                h[q*4+2] = fmaf(__expf(dtv * A[q*4+2]), h[q*4+2], dx * Bv.z);
                h[q*4+3] = fmaf(__expf(dtv * A[q*4+3]), h[q*4+3], dx * Bv.w);
                y = fmaf(h[q*4+0], Cv.x, y);
                y = fmaf(h[q*4+1], Cv.y, y);
                y = fmaf(h[q*4+2], Cv.z, y);
                y = fmaf(h[q*4+3], Cv.w, y);
            }
            y_p[(size_t)t * 2048] = (y + cx[j] * Dv) * siluf_(cz[j]);
        }
    };
    batch(0, xA, zA, dA, xB, zB, dB, true);
    batch(1, xB, zB, dB, xA, zA, dA, true);
    batch(2, xA, zA, dA, xB, zB, dB, true);
    batch(3, xB, zB, dB, xA, zA, dA, false);
}

// ---------------------------------------------------------------------------
// Heads
// ---------------------------------------------------------------------------
__global__ __launch_bounds__(256)
void head1_kernel(const float* __restrict__ x,
                  const float* __restrict__ w,
                  const float* __restrict__ bias,
                  float* __restrict__ hh)
{
    const int tid = threadIdx.x;
    const int jl  = tid >> 4;
    const int ks  = tid & 15;
    const int j   = blockIdx.x * 16 + jl;

    const float* wr = w + (size_t)j * 512 + ks * 32;
    float acc[8];
    #pragma unroll
    for (int b = 0; b < 8; b++) {
        const float* xr = x + ((size_t)b * 1024 + 1023) * 512 + ks * 32;
        float a = 0.f;
        #pragma unroll
        for (int k = 0; k < 32; k += 4) {
            const float4 wv = *reinterpret_cast<const float4*>(&wr[k]);
            const float4 xv = *reinterpret_cast<const float4*>(&xr[k]);
            a = fmaf(wv.x, xv.x, a); a = fmaf(wv.y, xv.y, a);
            a = fmaf(wv.z, xv.z, a); a = fmaf(wv.w, xv.w, a);
        }
        acc[b] = a;
    }
    #pragma unroll
    for (int b = 0; b < 8; b++) {
        float p = acc[b];
        p += __shfl_xor(p, 1);
        p += __shfl_xor(p, 2);
        p += __shfl_xor(p, 4);
        p += __shfl_xor(p, 8);
        if (ks == 0) hh[b * 256 + j] = fmaxf(p + bias[j], 0.f);
    }
}

__global__ void head2_kernel(const float* __restrict__ hh,
                             const float* __restrict__ w,
                             const float* __restrict__ b2,
                             float* __restrict__ out)
{
    const int t = threadIdx.x;
    if (t < 72) {
        const int bb = t / 9, a = t % 9;
        const float* hr = hh + bb * 256;
        const float* wr = w + a * 256;
        float acc = b2[a];
        for (int jj = 0; jj < 256; jj++) acc = fmaf(hr[jj], wr[jj], acc);
        out[t] = acc;
    }
}

// ---------------------------------------------------------------------------

extern "C" void kernel_launch(void* const* d_in, const int* in_sizes, int n_in,
                              void* d_out, int out_size, void* d_ws, size_t ws_size,
                              hipStream_t stream)
{
    const float* state     = (const float*)d_in[0];
    const float* embed_w   = (const float*)d_in[1];
    const float* embed_b   = (const float*)d_in[2];
    const float* in_proj_w = (const float*)d_in[3];
    const float* conv_w    = (const float*)d_in[4];
    const float* conv_b    = (const float*)d_in[5];
    const float* x_proj_w  = (const float*)d_in[6];
    const float* dt_proj_w = (const float*)d_in[7];
    const float* dt_proj_b = (const float*)d_in[8];
    const float* A_log     = (const float*)d_in[9];
    const float* Dp        = (const float*)d_in[10];
    const float* out_proj_w= (const float*)d_in[11];
    const float* h1w       = (const float*)d_in[12];
    const float* h1b       = (const float*)d_in[13];
    const float* h2w       = (const float*)d_in[14];
    const float* h2b       = (const float*)d_in[15];
    float* out = (float*)d_out;

    // fp32 workspace
    float* x    = (float*)d_ws;                   // 8192*512 = 4,194,304
    float* xz   = x    + (size_t)8192 * 512;      // 8192*2048
    float* xi   = xz   + (size_t)8192 * 2048;     // 8192*1024
    float* dtbf = xi   + (size_t)8192 * 1024;     // 8192*1024  (dt values)
    float* dbl  = dtbf + (size_t)8192 * 1024;     // 8192*64
    float* hh   = dbl  + (size_t)8192 * 64;       // 2048
    // bf16 hi/lo weight planes (ushort)
    ushort* wl = (ushort*)(hh + 2048);            // 3,276,800 ushorts
    ushort* we_hi = wl + 3276800;                 // embed: 131072 + 131072
    ushort* we_lo = we_hi + 131072;
    float* dtsum = (float*)(we_lo + 131072);      // B*NC*1024 = 262,144 floats

    // x region is dead between in_proj and out_proj: xp partials (4.19M,
    // exact fit), then hbuf (B*NC*1024*16 = 4.19M, exact fit).
    float* dblp = x;
    float* hbuf = x;

    const dim3 blk(256);

    // embed weights -> bf16 hi/lo, then embed GEMM (M=8192,N=512,K=256)
    wcvt_kernel<<<dim3(128), blk, 0, stream>>>(embed_w, we_hi, we_lo, 131072 / 4);
    gemm_mfma<1><<<dim3(4, 64), blk, 0, stream>>>(
        state, 256, we_hi, we_lo, 256, embed_b, x, 512, 256);

    for (int i = 0; i < 3; i++) {
        const float* Alog_i = A_log + (size_t)i * 1024 * 16;
        const float* dtw_i  = dt_proj_w + (size_t)i * 1024 * 32;
        const float* dtb_i  = dt_proj_b + (size_t)i * 1024;

        // convert this layer's weights (in/out/xp)
        wcvt3_kernel<<<dim3(1600), blk, 0, stream>>>(
            in_proj_w + (size_t)i * 2048 * 512,
            out_proj_w + (size_t)i * 512 * 1024,
            x_proj_w + (size_t)i * 64 * 1024, wl);

        // in_proj: xz = x @ in_w^T  (N=2048, K=512)
        gemm_mfma<0><<<dim3(16, 64), blk, 0, stream>>>(
            x, 512, wl, wl + 1048576, 512, nullptr, xz, 2048, 512);

        // causal depthwise conv + silu -> xi
        conv_silu_kernel<<<dim3(8 * 1024 * 1024 / 256), blk, 0, stream>>>(
            xz, conv_w + (size_t)i * 1024 * 4, conv_b + (size_t)i * 1024, xi);

        // x_proj: dbl = xi @ xw^T  (N=64, K=1024) — split-K MFMA + reduce
        gemm_mfma_xp<<<dim3(128, 8), blk, 0, stream>>>(
            xi, wl + 3145728, wl + 3211264, dblp);
        xp_reduce<<<dim3(2048), blk, 0, stream>>>(dblp, dbl);

        // dt = softplus(dt_proj(dbl)) — lean dedicated kernel
        dt_kernel<<<dim3(4, NC, 8), blk, 0, stream>>>(dbl, dtw_i, dtb_i, dtbf);

        // minimal chunked selective scan
        scan_p1<<<dim3(4, NC, 8), blk, 0, stream>>>(
            xi, dtbf, dbl, Alog_i, hbuf, dtsum);
        scan_p2<<<dim3(512), blk, 0, stream>>>(hbuf, dtsum, Alog_i);
        scan_p3<<<dim3(4, NC, 8), blk, 0, stream>>>(
            xi, dtbf, dbl, xz, Alog_i, Dp + (size_t)i * 1024, hbuf);

        // out_proj: x = y @ ow^T  (N=512, K=1024; A = xz with lda=2048)
        gemm_mfma<0><<<dim3(4, 64), blk, 0, stream>>>(
            xz, 2048, wl + 2097152, wl + 2621440, 1024, nullptr, x, 512, 1024);
    }

    head1_kernel<<<dim3(16), blk, 0, stream>>>(x, h1w, h1b, hh);
    head2_kernel<<<dim3(1), dim3(128), 0, stream>>>(hh, h2w, h2b, out);
}